// Round 1
// baseline (15982.620 us; speedup 1.0000x reference)
//
#include <hip/hip_runtime.h>
#include <hip/hip_bf16.h>

typedef __attribute__((ext_vector_type(4))) _Float16 half4;
typedef __attribute__((ext_vector_type(4))) float f32x4;

#define T_ 512
#define B_ 256
#define I_ 64
#define H_ 512
#define G_ 2048

// Pack W_ih | W_hh (fp32, [G][K0] and [G][512]) into per-lane MFMA fragment order, fp16.
// Layout: Wp[ ((jt*4+q)*nks + ks)*256 + l*4 + i ] = W[g][k]
//   g = q*512 + jt*16 + (l&15),  k = ks*16 + (l>>4)*4 + i
__global__ void pack_w(const float* __restrict__ Wih, const float* __restrict__ Whh,
                       int K0, int nks, _Float16* __restrict__ Wp) {
    int idx = blockIdx.x * 256 + threadIdx.x;
    int i  = idx & 3;
    int l  = (idx >> 2) & 63;
    int ks = (idx >> 8) % nks;
    int r  = (idx >> 8) / nks;     // jt*4 + q
    int q  = r & 3;
    int jt = r >> 2;
    int g  = q * H_ + jt * 16 + (l & 15);
    int k  = ks * 16 + (l >> 4) * 4 + i;
    float v = (k < K0) ? Wih[(size_t)g * K0 + k] : Whh[(size_t)g * H_ + (k - K0)];
    Wp[idx] = (_Float16)v;
}

__global__ void bias_kernel(const float* bi0, const float* bh0, const float* bi1, const float* bh1,
                            float* bias0, float* bias1) {
    int g = blockIdx.x * 256 + threadIdx.x;
    if (g < G_) {
        bias0[g] = bi0[g] + bh0[g];
        bias1[g] = bi1[g] + bh1[g];
    }
}

// One LSTM timestep for one layer.
// gates[b][g] = bias[g] + sum_k A0[b][k] * W0[k][g] + sum_k A1[b][k] * W1[k][g]
// A0: XF32 ? fp32 x-slice (row stride a0_stride) : fp16 h (row stride a0_stride)
// A1: fp16 h_prev [B][512]
// Block: (jt, bt) -> hidden cols [jt*16, jt*16+16), batch rows [bt*32, bt*32+32)
// 4 waves, wave w = gate quarter q. Each wave: 2 M-strips (rows 0-15, 16-31) x 16 cols.
template<int K0, bool XF32>
__global__ __launch_bounds__(256) void lstm_step(
    const void* __restrict__ A0v, int a0_stride,
    const _Float16* __restrict__ A1,
    const _Float16* __restrict__ Wp,
    const float* __restrict__ bias,
    float* __restrict__ c,
    _Float16* __restrict__ h_out)
{
    constexpr int NKS0 = K0 / 16;
    constexpr int NKS1 = H_ / 16;
    constexpr int NKS  = NKS0 + NKS1;

    const int jt = blockIdx.x;       // 0..31
    const int bt = blockIdx.y;       // 0..7
    const int btile = bt * 32;
    const int tid = threadIdx.x;
    const int w  = tid >> 6;         // gate quarter q
    const int l  = tid & 63;
    const int lr = l & 15;
    const int lk = l >> 4;

    f32x4 acc0 = {0.f, 0.f, 0.f, 0.f};
    f32x4 acc1 = {0.f, 0.f, 0.f, 0.f};

    const _Float16* wptr = Wp + ((size_t)(jt * 4 + w) * NKS) * 256 + l * 4;

    // ---- phase 0: A0 source (x for layer0, h1_new for layer1) ----
    if (XF32) {
        const float* x0 = (const float*)A0v + (size_t)(btile + lr) * a0_stride + lk * 4;
        #pragma unroll
        for (int ks = 0; ks < NKS0; ++ks) {
            half4 bf = *(const half4*)(wptr + ks * 256);
            f32x4 v0 = *(const f32x4*)(x0 + ks * 16);
            f32x4 v1 = *(const f32x4*)(x0 + (size_t)16 * a0_stride + ks * 16);
            half4 a0f = {(_Float16)v0[0], (_Float16)v0[1], (_Float16)v0[2], (_Float16)v0[3]};
            half4 a1f = {(_Float16)v1[0], (_Float16)v1[1], (_Float16)v1[2], (_Float16)v1[3]};
            acc0 = __builtin_amdgcn_mfma_f32_16x16x16f16(a0f, bf, acc0, 0, 0, 0);
            acc1 = __builtin_amdgcn_mfma_f32_16x16x16f16(a1f, bf, acc1, 0, 0, 0);
        }
    } else {
        const _Float16* a0p = (const _Float16*)A0v + (size_t)(btile + lr) * a0_stride + lk * 4;
        #pragma unroll 8
        for (int ks = 0; ks < NKS0; ++ks) {
            half4 bf  = *(const half4*)(wptr + ks * 256);
            half4 a0f = *(const half4*)(a0p + ks * 16);
            half4 a1f = *(const half4*)(a0p + (size_t)16 * a0_stride + ks * 16);
            acc0 = __builtin_amdgcn_mfma_f32_16x16x16f16(a0f, bf, acc0, 0, 0, 0);
            acc1 = __builtin_amdgcn_mfma_f32_16x16x16f16(a1f, bf, acc1, 0, 0, 0);
        }
    }

    // ---- phase 1: A1 source (h_prev of this layer) ----
    {
        const _Float16* a1p = A1 + (size_t)(btile + lr) * H_ + lk * 4;
        #pragma unroll 8
        for (int ks = 0; ks < NKS1; ++ks) {
            half4 bf  = *(const half4*)(wptr + (NKS0 + ks) * 256);
            half4 a0f = *(const half4*)(a1p + ks * 16);
            half4 a1f = *(const half4*)(a1p + 16 * H_ + ks * 16);
            acc0 = __builtin_amdgcn_mfma_f32_16x16x16f16(a0f, bf, acc0, 0, 0, 0);
            acc1 = __builtin_amdgcn_mfma_f32_16x16x16f16(a1f, bf, acc1, 0, 0, 0);
        }
    }

    // ---- epilogue: exchange quarters via LDS, apply LSTM cell ----
    __shared__ float gbuf[4 * 32 * 16];   // [q][row 0..31][col 0..15]
    #pragma unroll
    for (int r = 0; r < 4; ++r) {
        gbuf[(w * 32 +      4 * lk + r) * 16 + lr] = acc0[r];
        gbuf[(w * 32 + 16 + 4 * lk + r) * 16 + lr] = acc1[r];
    }
    __syncthreads();

    #pragma unroll
    for (int p = tid; p < 512; p += 256) {
        int row = p >> 4;
        int col = p & 15;
        int gcol = jt * 16 + col;
        float gi = gbuf[(0 * 32 + row) * 16 + col] + bias[0 * H_ + gcol];
        float gf = gbuf[(1 * 32 + row) * 16 + col] + bias[1 * H_ + gcol];
        float gg = gbuf[(2 * 32 + row) * 16 + col] + bias[2 * H_ + gcol];
        float go = gbuf[(3 * 32 + row) * 16 + col] + bias[3 * H_ + gcol];
        float ig = 1.f / (1.f + __expf(-gi));
        float fg = 1.f / (1.f + __expf(-gf));
        float gt = tanhf(gg);
        float og = 1.f / (1.f + __expf(-go));
        int ci = (btile + row) * H_ + gcol;
        float cn = fg * c[ci] + ig * gt;
        c[ci] = cn;
        h_out[ci] = (_Float16)(og * tanhf(cn));
    }
}

__global__ void fc_kernel(const _Float16* __restrict__ h2, const float* __restrict__ Wfc,
                          const float* __restrict__ bfc, float* __restrict__ out) {
    int b = blockIdx.x;
    int l = threadIdx.x;  // 64
    float s = 0.f;
    #pragma unroll
    for (int h = l; h < H_; h += 64) s += (float)h2[b * H_ + h] * Wfc[h];
    #pragma unroll
    for (int off = 32; off; off >>= 1) s += __shfl_down(s, off);
    if (l == 0) out[b] = s + bfc[0];
}

extern "C" void kernel_launch(void* const* d_in, const int* in_sizes, int n_in,
                              void* d_out, int out_size, void* d_ws, size_t ws_size,
                              hipStream_t stream) {
    const float* x    = (const float*)d_in[0];
    const float* Wih0 = (const float*)d_in[1];
    const float* Whh0 = (const float*)d_in[2];
    const float* bih0 = (const float*)d_in[3];
    const float* bhh0 = (const float*)d_in[4];
    const float* Wih1 = (const float*)d_in[5];
    const float* Whh1 = (const float*)d_in[6];
    const float* bih1 = (const float*)d_in[7];
    const float* bhh1 = (const float*)d_in[8];
    const float* Wfc  = (const float*)d_in[9];
    const float* bfc  = (const float*)d_in[10];
    float* out = (float*)d_out;

    char* ws = (char*)d_ws;
    // state block (zeroed each call): c1,c2 fp32 + h1[2],h2[2] fp16 = 2 MB
    float*    c1    = (float*)(ws);
    float*    c2    = (float*)(ws + 524288);
    _Float16* h1b[2] = { (_Float16*)(ws + 1048576), (_Float16*)(ws + 1048576 + 262144) };
    _Float16* h2b[2] = { (_Float16*)(ws + 1572864), (_Float16*)(ws + 1572864 + 262144) };
    float*    bias0 = (float*)(ws + 2097152);
    float*    bias1 = (float*)(ws + 2105344);
    _Float16* Wp0   = (_Float16*)(ws + 2113536);   // 2048*576*2  = 2359296 B
    _Float16* Wp1   = (_Float16*)(ws + 4472832);   // 2048*1024*2 = 4194304 B -> ends 8667136

    hipMemsetAsync(d_ws, 0, 2097152, stream);
    pack_w<<<dim3((G_ * 576) / 256), 256, 0, stream>>>(Wih0, Whh0, I_, 36, Wp0);
    pack_w<<<dim3((G_ * 1024) / 256), 256, 0, stream>>>(Wih1, Whh1, H_, 64, Wp1);
    bias_kernel<<<8, 256, 0, stream>>>(bih0, bhh0, bih1, bhh1, bias0, bias1);

    dim3 grid(32, 8);
    int cur = 0;
    for (int t = 0; t < T_; ++t) {
        int nxt = cur ^ 1;
        lstm_step<I_, true ><<<grid, 256, 0, stream>>>(
            x + (size_t)t * I_, T_ * I_, h1b[cur], Wp0, bias0, c1, h1b[nxt]);
        lstm_step<H_, false><<<grid, 256, 0, stream>>>(
            h1b[nxt], H_, h2b[cur], Wp1, bias1, c2, h2b[nxt]);
        cur = nxt;
    }
    fc_kernel<<<B_, 64, 0, stream>>>(h2b[cur], Wfc, bfc, out);
}